// Round 3
// baseline (1135.332 us; speedup 1.0000x reference)
//
#include <hip/hip_runtime.h>
#include <hip/hip_bf16.h>

typedef __hip_bfloat16 bf16;
typedef __attribute__((ext_vector_type(8))) short bf16x8;  // 8 bf16 in 4 VGPRs
typedef __attribute__((ext_vector_type(4))) float f32x4;

// ---------------- bf16 split helpers (Ootomo bf16x3 scheme) ----------------

__device__ __forceinline__ short f2bf(float x) {  // RNE float->bf16 bits
    unsigned u = __float_as_uint(x);
    unsigned r = (u + 0x7FFFu + ((u >> 16) & 1u)) >> 16;
    return (short)r;
}
__device__ __forceinline__ float bf2f(short s) {
    return __uint_as_float(((unsigned)(unsigned short)s) << 16);
}

// Load 8 consecutive floats (16B-aligned), split into hi/lo bf16 fragments.
__device__ __forceinline__ void split8(const float* __restrict__ p, bool ok, bf16x8& hi,
                                       bf16x8& lo) {
    float v[8];
    if (ok) {
        float4 x0 = ((const float4*)p)[0];
        float4 x1 = ((const float4*)p)[1];
        v[0] = x0.x; v[1] = x0.y; v[2] = x0.z; v[3] = x0.w;
        v[4] = x1.x; v[5] = x1.y; v[6] = x1.z; v[7] = x1.w;
    } else {
#pragma unroll
        for (int j = 0; j < 8; j++) v[j] = 0.f;
    }
#pragma unroll
    for (int j = 0; j < 8; j++) {
        short hb = f2bf(v[j]);
        hi[j] = hb;
        lo[j] = f2bf(v[j] - bf2f(hb));
    }
}

__device__ __forceinline__ float fast_tanh(float x) {
    x = fminf(fmaxf(x, -15.f), 15.f);
    float t = __expf(2.f * x);
    return __fdividef(t - 1.f, t + 1.f);
}

__device__ __forceinline__ void fma4(float4& acc, float v, const float4& x) {
    acc.x = fmaf(v, x.x, acc.x);
    acc.y = fmaf(v, x.y, acc.y);
    acc.z = fmaf(v, x.z, acc.z);
    acc.w = fmaf(v, x.w, acc.w);
}

__device__ __forceinline__ void red4(float4& a) {
    a.x += __shfl_xor(a.x, 16); a.y += __shfl_xor(a.y, 16);
    a.z += __shfl_xor(a.z, 16); a.w += __shfl_xor(a.w, 16);
    a.x += __shfl_xor(a.x, 32); a.y += __shfl_xor(a.y, 32);
    a.z += __shfl_xor(a.z, 32); a.w += __shfl_xor(a.w, 32);
}

// ---------------- dtype forensics (masks / indices) ----------------
// modes: 0=u8/bool, 1=int32, 2=float32, 3=int64, 4=float64
__global__ __launch_bounds__(256) void forensic_kernel(const unsigned int* __restrict__ mask_w,
                                                       const unsigned int* __restrict__ idx_w,
                                                       int nw_mask, int nw_idx,
                                                       int* __restrict__ flags) {
    __shared__ int sm[6];
    int t = threadIdx.x;
    if (t < 6) sm[t] = 0;
    __syncthreads();
    int m_gt1 = 0, m_f32 = 0, m_f64 = 0, m_oddnz = 0, i_hi = 0, i_oddnz = 0;
    for (int i = t; i < nw_mask; i += 256) {
        unsigned int w = mask_w[i];
        if (w > 1u && w != 0x3F800000u && w != 0x3FF00000u) m_gt1++;
        if (w == 0x3F800000u) m_f32++;
        if ((i & 1) && w == 0x3FF00000u) m_f64++;
        if ((i & 1) && w != 0u) m_oddnz++;
    }
    for (int i = t; i < nw_idx; i += 256) {
        unsigned int v = idx_w[i];
        if (v >= 0x20000000u) i_hi++;
        if ((i & 1) && v != 0u) i_oddnz++;
    }
    atomicAdd(&sm[0], m_gt1);
    atomicAdd(&sm[1], m_f32);
    atomicAdd(&sm[2], m_f64);
    atomicAdd(&sm[3], m_oddnz);
    atomicAdd(&sm[4], i_hi);
    atomicAdd(&sm[5], i_oddnz);
    __syncthreads();
    if (t == 0) {
        int mmode;
        if (sm[1] > 50) mmode = 2;
        else if (sm[2] > 50) mmode = 4;
        else if (sm[0] > 50) mmode = 0;
        else if (sm[3] > 50) mmode = 1;
        else mmode = 3;
        int imode;
        if (sm[4] > (nw_idx * 3) / 4) imode = 2;
        else if (sm[4] > nw_idx / 4) imode = 4;
        else if (sm[5] > 50) imode = 1;
        else imode = 3;
        flags[0] = mmode;
        flags[1] = imode;
    }
}

__device__ __forceinline__ int fetch_idx(const void* p, int e, int mode) {
    switch (mode) {
        case 1: return ((const int*)p)[e];
        case 3: return (int)(((const long long*)p)[e]);
        case 2: return (int)(((const float*)p)[e]);
        default: return (int)(((const double*)p)[e]);
    }
}

__global__ __launch_bounds__(256) void conv_mask_kernel(const void* __restrict__ m,
                                                        const int* __restrict__ flags, int n,
                                                        unsigned char* __restrict__ out) {
    int mode = flags[0];
    int i = blockIdx.x * 256 + threadIdx.x;
    if (i >= n) return;
    bool v;
    switch (mode) {
        case 0: v = ((const unsigned char*)m)[i] != 0; break;
        case 1: v = ((const int*)m)[i] != 0; break;
        case 2: v = ((const float*)m)[i] != 0.f; break;
        case 3: v = ((const long long*)m)[i] != 0; break;
        default: v = ((const double*)m)[i] != 0.0; break;
    }
    out[i] = v ? 1 : 0;
}

// ---------------- CSR build: two-level bucket sort (round-2 fix) ----------------
// Round-2 counters: scatter_kernel 125us, WRITE_SIZE 153MB for 12.8MB payload
// (random 4B writes -> 64B line allocate each). Replace hist+scan+scatter with:
//  1) LDS bucket histogram (bucket = row>>shift, ~256 rows each)
//  2) single-block bucket scan
//  3) append edges to bucket regions (cursor-sequential writes -> lines fill)
//  4) per-bucket finalize: LDS row-hist + LDS scan + scatter into a ~32KB
//     L2-resident CSR window; emits row_ptr. No global random writes remain.

__global__ __launch_bounds__(256) void bucket_hist(const void* __restrict__ row,
                                                   const int* __restrict__ flags, int e_cnt,
                                                   int n, int shift, int nb,
                                                   int* __restrict__ bcnt) {
    __shared__ int hist[2048];
    int t = threadIdx.x;
    for (int i = t; i < nb; i += 256) hist[i] = 0;
    __syncthreads();
    int imode = flags[1];
    for (int e = blockIdx.x * 256 + t; e < e_cnt; e += gridDim.x * 256) {
        int r = fetch_idx(row, e, imode);
        if ((unsigned)r < (unsigned)n) atomicAdd(&hist[r >> shift], 1);
    }
    __syncthreads();
    for (int i = t; i < nb; i += 256)
        if (hist[i]) atomicAdd(&bcnt[i], hist[i]);
}

// bptr: in = counts, out = exclusive offsets; also fills bcur and row_ptr[n].
__global__ __launch_bounds__(1024) void bucket_scan(int* __restrict__ bptr, int nb,
                                                    int* __restrict__ bcur, int n,
                                                    int* __restrict__ row_ptr) {
    __shared__ int sh[1024];
    int t = threadIdx.x;
    int i0 = t * 2, i1 = t * 2 + 1;
    int a = (i0 < nb) ? bptr[i0] : 0;
    int b = (i1 < nb) ? bptr[i1] : 0;
    int s = a + b;
    sh[t] = s;
    __syncthreads();
    for (int off = 1; off < 1024; off <<= 1) {
        int u = (t >= off) ? sh[t - off] : 0;
        __syncthreads();
        sh[t] += u;
        __syncthreads();
    }
    int base = sh[t] - s;  // exclusive prefix
    if (i0 < nb) { bptr[i0] = base; bcur[i0] = base; }
    if (i1 < nb) { bptr[i1] = base + a; bcur[i1] = base + a; }
    if (t == 1023) {
        bptr[nb] = sh[1023];
        row_ptr[n] = sh[1023];
    }
}

__global__ __launch_bounds__(256) void bin_pass(const void* __restrict__ row,
                                                const void* __restrict__ col,
                                                const float* __restrict__ vals,
                                                const int* __restrict__ flags, int e_cnt, int n,
                                                int shift, int* __restrict__ bcur,
                                                int2* __restrict__ rcbin,
                                                float* __restrict__ valbin) {
    int imode = flags[1];
    int e = blockIdx.x * 256 + threadIdx.x;
    if (e >= e_cnt) return;
    int r = fetch_idx(row, e, imode);
    if ((unsigned)r >= (unsigned)n) return;
    int c = fetch_idx(col, e, imode);
    if ((unsigned)c >= (unsigned)n) c = 0;
    int pos = atomicAdd(&bcur[r >> shift], 1);
    rcbin[pos] = make_int2(r, c);
    valbin[pos] = vals[e];
}

// One block per bucket. rows-per-bucket <= 1024.
__global__ __launch_bounds__(256) void csr_finalize(const int* __restrict__ bptr,
                                                    const int2* __restrict__ rcbin,
                                                    const float* __restrict__ valbin, int n,
                                                    int shift, int* __restrict__ row_ptr,
                                                    int* __restrict__ col_s,
                                                    float* __restrict__ val_s) {
    __shared__ int cnt[1024];
    __shared__ int curs[1024];
    __shared__ int red[256];
    int b = blockIdx.x, t = threadIdx.x;
    int rpb = 1 << shift;
    int r0 = b << shift;
    int rows = n - r0;
    if (rows <= 0) return;
    if (rows > rpb) rows = rpb;
    int ebase = bptr[b], eend = bptr[b + 1];
    for (int i = t; i < rows; i += 256) cnt[i] = 0;
    __syncthreads();
    for (int e = ebase + t; e < eend; e += 256) atomicAdd(&cnt[rcbin[e].x - r0], 1);
    __syncthreads();
    // exclusive scan of cnt[0..rows): 4 values per thread + block scan
    int v[4], s = 0;
#pragma unroll
    for (int j = 0; j < 4; j++) {
        int idx = t * 4 + j;
        v[j] = (idx < rows) ? cnt[idx] : 0;
        s += v[j];
    }
    red[t] = s;
    __syncthreads();
    for (int off = 1; off < 256; off <<= 1) {
        int u = (t >= off) ? red[t - off] : 0;
        __syncthreads();
        red[t] += u;
        __syncthreads();
    }
    int run = ebase + red[t] - s;
#pragma unroll
    for (int j = 0; j < 4; j++) {
        int idx = t * 4 + j;
        if (idx < rows) {
            row_ptr[r0 + idx] = run;
            curs[idx] = run;
            run += v[j];
        }
    }
    __syncthreads();
    for (int e = ebase + t; e < eend; e += 256) {
        int2 rc = rcbin[e];
        float vv = valbin[e];
        int pos = atomicAdd(&curs[rc.x - r0], 1);
        col_s[pos] = rc.y;
        val_s[pos] = vv;
    }
}

// ---------------- SpMM: ax = A @ x  (CSR, one wave per row) ----------------
// Latency-bound fix (round 1 counters: HBM 10%, VALU 19%): preload up to 64
// (col,val) per row into registers (1/lane), shfl-broadcast -> no load-to-
// address chain. 4 x 16-lane groups each gather a DIFFERENT edge as float4
// (16 lanes x 16B = 256B row), 2-deep unrolled = 8 gathers in flight/wave.

__global__ __launch_bounds__(256) void spmm_dual(const float* __restrict__ X,
                                                 const int* __restrict__ row_ptr,
                                                 const int* __restrict__ col_s,
                                                 const float* __restrict__ val_s,
                                                 const unsigned char* __restrict__ mask, int n,
                                                 float* __restrict__ ax_m,
                                                 float* __restrict__ ax_f) {
    int gid = blockIdx.x * 256 + threadIdx.x;
    int r = gid >> 6;
    if (r >= n) return;
    int lane = threadIdx.x & 63;
    int g = lane >> 4, sub = lane & 15;
    int s = row_ptr[r], e = row_ptr[r + 1];
    int cnt = e - s;
    int myc = 0;
    float myvf = 0.f, myvm = 0.f;
    if (lane < cnt) {
        myc = col_s[s + lane];
        float v = val_s[s + lane];
        myvf = v;
        myvm = mask[myc] ? 0.f : v;
    }
    int cmain = cnt > 64 ? 64 : cnt;
    float4 fA = {0, 0, 0, 0}, fB = {0, 0, 0, 0}, mA = {0, 0, 0, 0}, mB = {0, 0, 0, 0};
    for (int i = 0; i < cmain; i += 8) {
        int iA = i + g, iB = i + 4 + g;
        int cA = __shfl(myc, iA), cB = __shfl(myc, iB);
        float vfA = __shfl(myvf, iA), vfB = __shfl(myvf, iB);
        float vmA = __shfl(myvm, iA), vmB = __shfl(myvm, iB);
        if (iA < cmain) {
            float4 x = *(const float4*)(X + (size_t)cA * 64 + sub * 4);
            fma4(fA, vfA, x);
            fma4(mA, vmA, x);
        }
        if (iB < cmain) {
            float4 x = *(const float4*)(X + (size_t)cB * 64 + sub * 4);
            fma4(fB, vfB, x);
            fma4(mB, vmB, x);
        }
    }
    for (int i = 64 + g; i < cnt; i += 4) {  // rare overflow rows
        int c = col_s[s + i];
        float v = val_s[s + i];
        float vm = mask[c] ? 0.f : v;
        float4 x = *(const float4*)(X + (size_t)c * 64 + sub * 4);
        fma4(fA, v, x);
        fma4(mA, vm, x);
    }
    fA.x += fB.x; fA.y += fB.y; fA.z += fB.z; fA.w += fB.w;
    mA.x += mB.x; mA.y += mB.y; mA.z += mB.z; mA.w += mB.w;
    red4(fA);
    red4(mA);
    if (g == 0) {
        *(float4*)(ax_f + (size_t)r * 64 + sub * 4) = fA;
        *(float4*)(ax_m + (size_t)r * 64 + sub * 4) = mA;
    }
}

// Single-output masked SpMM; masked edges skip the gather entirely
// (group-uniform predicate -> no memory transaction issued).
__global__ __launch_bounds__(256) void spmm_one(const float* __restrict__ X,
                                                const int* __restrict__ row_ptr,
                                                const int* __restrict__ col_s,
                                                const float* __restrict__ val_s,
                                                const unsigned char* __restrict__ mask, int n,
                                                float* __restrict__ ax) {
    int gid = blockIdx.x * 256 + threadIdx.x;
    int r = gid >> 6;
    if (r >= n) return;
    int lane = threadIdx.x & 63;
    int g = lane >> 4, sub = lane & 15;
    int s = row_ptr[r], e = row_ptr[r + 1];
    int cnt = e - s;
    int myc = 0;
    float myv = 0.f;
    if (lane < cnt) {
        myc = col_s[s + lane];
        float v = val_s[s + lane];
        myv = mask[myc] ? 0.f : v;
    }
    int cmain = cnt > 64 ? 64 : cnt;
    float4 aA = {0, 0, 0, 0}, aB = {0, 0, 0, 0};
    for (int i = 0; i < cmain; i += 8) {
        int iA = i + g, iB = i + 4 + g;
        int cA = __shfl(myc, iA), cB = __shfl(myc, iB);
        float vA = __shfl(myv, iA), vB = __shfl(myv, iB);
        if (iA < cmain && vA != 0.f) {
            float4 x = *(const float4*)(X + (size_t)cA * 64 + sub * 4);
            fma4(aA, vA, x);
        }
        if (iB < cmain && vB != 0.f) {
            float4 x = *(const float4*)(X + (size_t)cB * 64 + sub * 4);
            fma4(aB, vB, x);
        }
    }
    for (int i = 64 + g; i < cnt; i += 4) {
        int c = col_s[s + i];
        if (mask[c]) continue;
        float v = val_s[s + i];
        float4 x = *(const float4*)(X + (size_t)c * 64 + sub * 4);
        fma4(aA, v, x);
    }
    aA.x += aB.x; aA.y += aB.y; aA.z += aB.z; aA.w += aB.w;
    red4(aA);
    if (g == 0) *(float4*)(ax + (size_t)r * 64 + sub * 4) = aA;
}

// ---------------- fused kernel A: embed GEMM (bias+PReLU) -> LDS -> fc GEMM -> tanh-sum -----
// embed tile (16 rows x 64 cols, f32, stride 68 -> conflict-free b128 reads)
// lives only in LDS. s_sums[p][k] += sum_rows tanh(fc(embed)).

template <int PP>
__global__ __launch_bounds__(256) void gemm_tanh(const float* __restrict__ X,
                                                 const float* __restrict__ Wg,
                                                 const float* __restrict__ b,
                                                 const float* __restrict__ a,
                                                 const float* __restrict__ fcw,
                                                 const float* __restrict__ fcb, int n,
                                                 float* __restrict__ s_sums) {
    __shared__ __align__(16) float tile[PP][16][68];
    int t = threadIdx.x;
    int wv = t >> 6, lane = t & 63, nl = lane & 15, q = lane >> 4;
    int colg = wv * 16 + nl;
    bf16x8 whi[PP][2], wlo[PP][2];
    float bias[PP], slope[PP];
#pragma unroll
    for (int p = 0; p < PP; p++) {
#pragma unroll
        for (int kk = 0; kk < 2; kk++)
            split8(Wg + p * 4096 + colg * 64 + kk * 32 + q * 8, true, whi[p][kk], wlo[p][kk]);
        bias[p] = b[p * 64 + colg];
        slope[p] = a[p];
    }
    bf16x8 fhi[2], flo[2];
#pragma unroll
    for (int kk = 0; kk < 2; kk++)
        split8(fcw + colg * 64 + kk * 32 + q * 8, true, fhi[kk], flo[kk]);
    float fbias = fcb[colg];
    float ssum[PP];
#pragma unroll
    for (int p = 0; p < PP; p++) ssum[p] = 0.f;

    int ntiles = (n + 15) >> 4;
    for (int rt = blockIdx.x; rt < ntiles; rt += gridDim.x) {
        int rowi = rt * 16 + nl;
        bool ok = rowi < n;
        bf16x8 ah[2], al[2];
#pragma unroll
        for (int kk = 0; kk < 2; kk++)
            split8(X + (size_t)rowi * 64 + kk * 32 + q * 8, ok, ah[kk], al[kk]);
#pragma unroll
        for (int p = 0; p < PP; p++) {
            f32x4 acc = {0.f, 0.f, 0.f, 0.f};
            acc = __builtin_amdgcn_mfma_f32_16x16x32_bf16(ah[0], whi[p][0], acc, 0, 0, 0);
            acc = __builtin_amdgcn_mfma_f32_16x16x32_bf16(ah[1], whi[p][1], acc, 0, 0, 0);
            acc = __builtin_amdgcn_mfma_f32_16x16x32_bf16(al[0], whi[p][0], acc, 0, 0, 0);
            acc = __builtin_amdgcn_mfma_f32_16x16x32_bf16(al[1], whi[p][1], acc, 0, 0, 0);
            acc = __builtin_amdgcn_mfma_f32_16x16x32_bf16(ah[0], wlo[p][0], acc, 0, 0, 0);
            acc = __builtin_amdgcn_mfma_f32_16x16x32_bf16(ah[1], wlo[p][1], acc, 0, 0, 0);
            acc = __builtin_amdgcn_mfma_f32_16x16x32_bf16(al[0], wlo[p][0], acc, 0, 0, 0);
            acc = __builtin_amdgcn_mfma_f32_16x16x32_bf16(al[1], wlo[p][1], acc, 0, 0, 0);
#pragma unroll
            for (int i = 0; i < 4; i++) {
                float o = acc[i] + bias[p];
                tile[p][q * 4 + i][colg] = (o > 0.f) ? o : slope[p] * o;
            }
        }
        __syncthreads();
#pragma unroll
        for (int p = 0; p < PP; p++) {
            bf16x8 eh[2], el[2];
#pragma unroll
            for (int kk = 0; kk < 2; kk++)
                split8(&tile[p][nl][kk * 32 + q * 8], true, eh[kk], el[kk]);
            f32x4 acc = {0.f, 0.f, 0.f, 0.f};
            acc = __builtin_amdgcn_mfma_f32_16x16x32_bf16(eh[0], fhi[0], acc, 0, 0, 0);
            acc = __builtin_amdgcn_mfma_f32_16x16x32_bf16(eh[1], fhi[1], acc, 0, 0, 0);
            acc = __builtin_amdgcn_mfma_f32_16x16x32_bf16(el[0], fhi[0], acc, 0, 0, 0);
            acc = __builtin_amdgcn_mfma_f32_16x16x32_bf16(el[1], fhi[1], acc, 0, 0, 0);
            acc = __builtin_amdgcn_mfma_f32_16x16x32_bf16(eh[0], flo[0], acc, 0, 0, 0);
            acc = __builtin_amdgcn_mfma_f32_16x16x32_bf16(eh[1], flo[1], acc, 0, 0, 0);
#pragma unroll
            for (int i = 0; i < 4; i++) {
                int r = rt * 16 + q * 4 + i;
                if (r < n) ssum[p] += fast_tanh(acc[i] + fbias);
            }
        }
        __syncthreads();
    }
#pragma unroll
    for (int p = 0; p < PP; p++) {
        float s = ssum[p];
        s += __shfl_xor(s, 16);
        s += __shfl_xor(s, 32);
        if (q == 0) atomicAdd(&s_sums[p * 64 + colg], s);
    }
}

// ---------------- fused kernel B: recompute embed GEMM, mix with beta, write out -----------

template <int PP>
__global__ __launch_bounds__(256) void gemm_mix(const float* __restrict__ X,
                                                const float* __restrict__ Wg,
                                                const float* __restrict__ b,
                                                const float* __restrict__ a,
                                                const float* __restrict__ beta, int n,
                                                float* __restrict__ out, int accum) {
    int t = threadIdx.x;
    int wv = t >> 6, lane = t & 63, nl = lane & 15, q = lane >> 4;
    int colg = wv * 16 + nl;
    bf16x8 whi[PP][2], wlo[PP][2];
    float bias[PP], slope[PP], bet[PP];
#pragma unroll
    for (int p = 0; p < PP; p++) {
#pragma unroll
        for (int kk = 0; kk < 2; kk++)
            split8(Wg + p * 4096 + colg * 64 + kk * 32 + q * 8, true, whi[p][kk], wlo[p][kk]);
        bias[p] = b[p * 64 + colg];
        slope[p] = a[p];
        bet[p] = beta[p];
    }
    int ntiles = (n + 15) >> 4;
    for (int rt = blockIdx.x; rt < ntiles; rt += gridDim.x) {
        int rowi = rt * 16 + nl;
        bool ok = rowi < n;
        bf16x8 ah[2], al[2];
#pragma unroll
        for (int kk = 0; kk < 2; kk++)
            split8(X + (size_t)rowi * 64 + kk * 32 + q * 8, ok, ah[kk], al[kk]);
        float mix[4] = {0.f, 0.f, 0.f, 0.f};
#pragma unroll
        for (int p = 0; p < PP; p++) {
            f32x4 acc = {0.f, 0.f, 0.f, 0.f};
            acc = __builtin_amdgcn_mfma_f32_16x16x32_bf16(ah[0], whi[p][0], acc, 0, 0, 0);
            acc = __builtin_amdgcn_mfma_f32_16x16x32_bf16(ah[1], whi[p][1], acc, 0, 0, 0);
            acc = __builtin_amdgcn_mfma_f32_16x16x32_bf16(al[0], whi[p][0], acc, 0, 0, 0);
            acc = __builtin_amdgcn_mfma_f32_16x16x32_bf16(al[1], whi[p][1], acc, 0, 0, 0);
            acc = __builtin_amdgcn_mfma_f32_16x16x32_bf16(ah[0], wlo[p][0], acc, 0, 0, 0);
            acc = __builtin_amdgcn_mfma_f32_16x16x32_bf16(ah[1], wlo[p][1], acc, 0, 0, 0);
            acc = __builtin_amdgcn_mfma_f32_16x16x32_bf16(al[0], wlo[p][0], acc, 0, 0, 0);
            acc = __builtin_amdgcn_mfma_f32_16x16x32_bf16(al[1], wlo[p][1], acc, 0, 0, 0);
#pragma unroll
            for (int i = 0; i < 4; i++) {
                float o = acc[i] + bias[p];
                o = (o > 0.f) ? o : slope[p] * o;
                mix[i] = fmaf(bet[p], o, mix[i]);
            }
        }
#pragma unroll
        for (int i = 0; i < 4; i++) {
            int r = rt * 16 + q * 4 + i;
            if (r < n) {
                size_t idx = (size_t)r * 64 + colg;
                out[idx] = accum ? (out[idx] + mix[i]) : mix[i];
            }
        }
    }
}

__global__ __launch_bounds__(64) void compute_beta(const float* __restrict__ s_sums,
                                                   const float* __restrict__ att, int n, int P,
                                                   float* __restrict__ beta) {
    int lane = threadIdx.x;
    float av = att[lane];
    float l[8];
    for (int p = 0; p < P; p++) l[p] = s_sums[p * 64 + lane] * av;
#pragma unroll
    for (int off = 32; off > 0; off >>= 1)
        for (int p = 0; p < 8; p++)
            if (p < P) l[p] += __shfl_down(l[p], off);
    if (lane == 0) {
        const float inv = 1.0f / (float)n;
        float m = -1e30f;
        for (int p = 0; p < P; p++) {
            l[p] *= inv;
            m = fmaxf(m, l[p]);
        }
        float s = 0.f;
        for (int p = 0; p < P; p++) {
            l[p] = __expf(l[p] - m);
            s += l[p];
        }
        for (int p = 0; p < P; p++) beta[p] = l[p] / s;
    }
}

// ---------------- driver ----------------

extern "C" void kernel_launch(void* const* d_in, const int* in_sizes, int n_in,
                              void* d_out, int out_size, void* d_ws, size_t ws_size,
                              hipStream_t stream) {
    const float* h = (const float*)d_in[0];
    const float* W = (const float*)d_in[1];
    const float* b = (const float*)d_in[2];
    const float* a = (const float*)d_in[3];
    const float* fc_w = (const float*)d_in[4];
    const float* fc_b = (const float*)d_in[5];
    const float* att = (const float*)d_in[6];
    const float* adj = (const float*)d_in[7];
    const void* row = d_in[8];
    const void* col = d_in[9];
    const void* mask1 = d_in[10];
    const void* mask2 = d_in[11];
    float* out = (float*)d_out;

    int P = in_sizes[3];
    if (P < 1 || P > 8) P = 3;
    int N = in_sizes[0] / 64;
    int E = in_sizes[7];

    // bucket geometry: rows/bucket = 1<<shift, buckets <= 2048, rows/bucket <= 1024
    int shift = 8;
    while (((N >> shift) + 1) > 2048) shift++;
    int NB = (N >> shift) + 1;

    char* w = (char*)d_ws;
    auto alloc = [&](size_t bytes) {
        void* p = (void*)w;
        w += (bytes + 255) & ~(size_t)255;
        return p;
    };
    int* row_ptr = (int*)alloc((size_t)(N + 1) * 4);
    int* col_s = (int*)alloc((size_t)E * 4);
    float* val_s = (float*)alloc((size_t)E * 4);
    int* bptr = (int*)alloc((size_t)(NB + 1) * 4);
    int* bcur = (int*)alloc((size_t)NB * 4);
    int2* rcbin = (int2*)alloc((size_t)E * 8);
    float* valbin = (float*)alloc((size_t)E * 4);
    unsigned char* m1c = (unsigned char*)alloc(N);
    unsigned char* m2c = (unsigned char*)alloc(N);
    float* axm = (float*)alloc((size_t)N * 64 * 4);  // A @ (x * ~mask)
    float* axf = (float*)alloc((size_t)N * 64 * 4);  // A @ x
    float* s_sums = (float*)alloc(8 * 64 * 4);
    float* beta = (float*)alloc(8 * 4);
    int* flags = (int*)alloc(256);

    int nw_mask = N / 4 > 25000 ? 25000 : N / 4;
    int nw_idx = E / 4 > 25000 ? 25000 : E / 4;
    forensic_kernel<<<1, 256, 0, stream>>>((const unsigned int*)mask1, (const unsigned int*)row,
                                           nw_mask, nw_idx, flags);
    conv_mask_kernel<<<(N + 255) / 256, 256, 0, stream>>>(mask1, flags, N, m1c);
    conv_mask_kernel<<<(N + 255) / 256, 256, 0, stream>>>(mask2, flags, N, m2c);

    hipMemsetAsync(bptr, 0, (size_t)(NB + 1) * 4, stream);
    bucket_hist<<<1024, 256, 0, stream>>>(row, flags, E, N, shift, NB, bptr);
    bucket_scan<<<1, 1024, 0, stream>>>(bptr, NB, bcur, N, row_ptr);
    bin_pass<<<(E + 255) / 256, 256, 0, stream>>>(row, col, adj, flags, E, N, shift, bcur, rcbin,
                                                  valbin);
    csr_finalize<<<NB, 256, 0, stream>>>(bptr, rcbin, valbin, N, shift, row_ptr, col_s, val_s);

    int spmm_grid = ((size_t)N * 64 + 255) / 256;  // one wave per row
    int gemm_blocks = 1024;

    // tail: ax -> [A: embed GEMM + fc + tanh-sum] -> beta -> [B: recompute + mix]
    auto tail = [&](const float* ax, float* dst) {
        hipMemsetAsync(s_sums, 0, 8 * 64 * 4, stream);
        if (P == 3) {
            gemm_tanh<3><<<gemm_blocks, 256, 0, stream>>>(ax, W, b, a, fc_w, fc_b, N, s_sums);
        } else {
            for (int p = 0; p < P; p++)
                gemm_tanh<1><<<gemm_blocks, 256, 0, stream>>>(ax, W + p * 4096, b + p * 64, a + p,
                                                              fc_w, fc_b, N, s_sums + p * 64);
        }
        compute_beta<<<1, 64, 0, stream>>>(s_sums, att, N, P, beta);
        if (P == 3) {
            gemm_mix<3><<<gemm_blocks, 256, 0, stream>>>(ax, W, b, a, beta, N, dst, 0);
        } else {
            for (int p = 0; p < P; p++)
                gemm_mix<1><<<gemm_blocks, 256, 0, stream>>>(ax, W + p * 4096, b + p * 64, a + p,
                                                             beta + p, N, dst, p != 0);
        }
    };

    // pass 0 + 1 share one edge sweep: ax_masked and ax_full from a single gather
    spmm_dual<<<spmm_grid, 256, 0, stream>>>(h, row_ptr, col_s, val_s, m1c, N, axm, axf);
    tail(axm, out);                       // z_mp
    tail(axf, out + (size_t)N * 64);      // z_mp2
    // pass 2 decodes from z_mp (in d_out), masked by mask2 (gather skipped when masked)
    spmm_one<<<spmm_grid, 256, 0, stream>>>(out, row_ptr, col_s, val_s, m2c, N, axm);
    tail(axm, out + (size_t)2 * N * 64);  // x_recon
}

// Round 4
// 655.693 us; speedup vs baseline: 1.7315x; 1.7315x over previous
//
#include <hip/hip_runtime.h>
#include <hip/hip_bf16.h>

typedef __hip_bfloat16 bf16;
typedef __attribute__((ext_vector_type(8))) short bf16x8;  // 8 bf16 in 4 VGPRs
typedef __attribute__((ext_vector_type(4))) float f32x4;

// ---------------- bf16 split helpers (Ootomo bf16x3 scheme) ----------------

__device__ __forceinline__ short f2bf(float x) {  // RNE float->bf16 bits
    unsigned u = __float_as_uint(x);
    unsigned r = (u + 0x7FFFu + ((u >> 16) & 1u)) >> 16;
    return (short)r;
}
__device__ __forceinline__ float bf2f(short s) {
    return __uint_as_float(((unsigned)(unsigned short)s) << 16);
}

// Load 8 consecutive floats (16B-aligned), split into hi/lo bf16 fragments.
__device__ __forceinline__ void split8(const float* __restrict__ p, bool ok, bf16x8& hi,
                                       bf16x8& lo) {
    float v[8];
    if (ok) {
        float4 x0 = ((const float4*)p)[0];
        float4 x1 = ((const float4*)p)[1];
        v[0] = x0.x; v[1] = x0.y; v[2] = x0.z; v[3] = x0.w;
        v[4] = x1.x; v[5] = x1.y; v[6] = x1.z; v[7] = x1.w;
    } else {
#pragma unroll
        for (int j = 0; j < 8; j++) v[j] = 0.f;
    }
#pragma unroll
    for (int j = 0; j < 8; j++) {
        short hb = f2bf(v[j]);
        hi[j] = hb;
        lo[j] = f2bf(v[j] - bf2f(hb));
    }
}

__device__ __forceinline__ float fast_tanh(float x) {
    x = fminf(fmaxf(x, -15.f), 15.f);
    float t = __expf(2.f * x);
    return __fdividef(t - 1.f, t + 1.f);
}

__device__ __forceinline__ void fma4(float4& acc, float v, const float4& x) {
    acc.x = fmaf(v, x.x, acc.x);
    acc.y = fmaf(v, x.y, acc.y);
    acc.z = fmaf(v, x.z, acc.z);
    acc.w = fmaf(v, x.w, acc.w);
}

__device__ __forceinline__ void red4(float4& a) {
    a.x += __shfl_xor(a.x, 16); a.y += __shfl_xor(a.y, 16);
    a.z += __shfl_xor(a.z, 16); a.w += __shfl_xor(a.w, 16);
    a.x += __shfl_xor(a.x, 32); a.y += __shfl_xor(a.y, 32);
    a.z += __shfl_xor(a.z, 32); a.w += __shfl_xor(a.w, 32);
}

// ---------------- dtype forensics (masks / indices) ----------------
// modes: 0=u8/bool, 1=int32, 2=float32, 3=int64, 4=float64
__global__ __launch_bounds__(256) void forensic_kernel(const unsigned int* __restrict__ mask_w,
                                                       const unsigned int* __restrict__ idx_w,
                                                       int nw_mask, int nw_idx,
                                                       int* __restrict__ flags) {
    __shared__ int sm[6];
    int t = threadIdx.x;
    if (t < 6) sm[t] = 0;
    __syncthreads();
    int m_gt1 = 0, m_f32 = 0, m_f64 = 0, m_oddnz = 0, i_hi = 0, i_oddnz = 0;
    for (int i = t; i < nw_mask; i += 256) {
        unsigned int w = mask_w[i];
        if (w > 1u && w != 0x3F800000u && w != 0x3FF00000u) m_gt1++;
        if (w == 0x3F800000u) m_f32++;
        if ((i & 1) && w == 0x3FF00000u) m_f64++;
        if ((i & 1) && w != 0u) m_oddnz++;
    }
    for (int i = t; i < nw_idx; i += 256) {
        unsigned int v = idx_w[i];
        if (v >= 0x20000000u) i_hi++;
        if ((i & 1) && v != 0u) i_oddnz++;
    }
    atomicAdd(&sm[0], m_gt1);
    atomicAdd(&sm[1], m_f32);
    atomicAdd(&sm[2], m_f64);
    atomicAdd(&sm[3], m_oddnz);
    atomicAdd(&sm[4], i_hi);
    atomicAdd(&sm[5], i_oddnz);
    __syncthreads();
    if (t == 0) {
        int mmode;
        if (sm[1] > 50) mmode = 2;
        else if (sm[2] > 50) mmode = 4;
        else if (sm[0] > 50) mmode = 0;
        else if (sm[3] > 50) mmode = 1;
        else mmode = 3;
        int imode;
        if (sm[4] > (nw_idx * 3) / 4) imode = 2;
        else if (sm[4] > nw_idx / 4) imode = 4;
        else if (sm[5] > 50) imode = 1;
        else imode = 3;
        flags[0] = mmode;
        flags[1] = imode;
    }
}

__device__ __forceinline__ int fetch_idx(const void* p, int e, int mode) {
    switch (mode) {
        case 1: return ((const int*)p)[e];
        case 3: return (int)(((const long long*)p)[e]);
        case 2: return (int)(((const float*)p)[e]);
        default: return (int)(((const double*)p)[e]);
    }
}

__global__ __launch_bounds__(256) void conv_mask_kernel(const void* __restrict__ m,
                                                        const int* __restrict__ flags, int n,
                                                        unsigned char* __restrict__ out) {
    int mode = flags[0];
    int i = blockIdx.x * 256 + threadIdx.x;
    if (i >= n) return;
    bool v;
    switch (mode) {
        case 0: v = ((const unsigned char*)m)[i] != 0; break;
        case 1: v = ((const int*)m)[i] != 0; break;
        case 2: v = ((const float*)m)[i] != 0.f; break;
        case 3: v = ((const long long*)m)[i] != 0; break;
        default: v = ((const double*)m)[i] != 0.0; break;
    }
    out[i] = v ? 1 : 0;
}

// ---------------- CSR build: two-level bucket sort, block-aggregated binning --------
// Round-3 post-mortem: per-edge global atomics on ~391 bucket cursors serialized
// (559us, HBM 2.6%, VALU 0.1%). Fix: each block owns a contiguous edge chunk,
// LDS-histograms it, reserves a contiguous range per bucket with ONE global
// atomic per (block,bucket), then scatters via LDS cursors -> ~250B contiguous
// writes per region, ~20 atomics per cursor address total.

__global__ __launch_bounds__(256) void bucket_hist(const void* __restrict__ row,
                                                   const int* __restrict__ flags, int e_cnt,
                                                   int n, int shift, int nb,
                                                   int* __restrict__ bcnt) {
    __shared__ int hist[2048];
    int t = threadIdx.x;
    for (int i = t; i < nb; i += 256) hist[i] = 0;
    __syncthreads();
    int imode = flags[1];
    for (int e = blockIdx.x * 256 + t; e < e_cnt; e += gridDim.x * 256) {
        int r = fetch_idx(row, e, imode);
        if ((unsigned)r < (unsigned)n) atomicAdd(&hist[r >> shift], 1);
    }
    __syncthreads();
    for (int i = t; i < nb; i += 256)
        if (hist[i]) atomicAdd(&bcnt[i], hist[i]);
}

// bptr: in = counts, out = exclusive offsets; also fills bcur and row_ptr[n].
__global__ __launch_bounds__(1024) void bucket_scan(int* __restrict__ bptr, int nb,
                                                    int* __restrict__ bcur, int n,
                                                    int* __restrict__ row_ptr) {
    __shared__ int sh[1024];
    int t = threadIdx.x;
    int i0 = t * 2, i1 = t * 2 + 1;
    int a = (i0 < nb) ? bptr[i0] : 0;
    int b = (i1 < nb) ? bptr[i1] : 0;
    int s = a + b;
    sh[t] = s;
    __syncthreads();
    for (int off = 1; off < 1024; off <<= 1) {
        int u = (t >= off) ? sh[t - off] : 0;
        __syncthreads();
        sh[t] += u;
        __syncthreads();
    }
    int base = sh[t] - s;  // exclusive prefix
    if (i0 < nb) { bptr[i0] = base; bcur[i0] = base; }
    if (i1 < nb) { bptr[i1] = base + a; bcur[i1] = base + a; }
    if (t == 1023) {
        bptr[nb] = sh[1023];
        row_ptr[n] = sh[1023];
    }
}

// Block-aggregated binning. Each block: [e0,e1) chunk of edges.
__global__ __launch_bounds__(256) void bin_pass2(const void* __restrict__ row,
                                                 const void* __restrict__ col,
                                                 const float* __restrict__ vals,
                                                 const int* __restrict__ flags, int e_cnt, int n,
                                                 int shift, int nb, int epb,
                                                 int* __restrict__ bcur,
                                                 int2* __restrict__ rcbin,
                                                 float* __restrict__ valbin) {
    __shared__ int hist[2048];
    __shared__ int base[2048];
    int t = threadIdx.x;
    int e0 = blockIdx.x * epb;
    int e1 = e0 + epb;
    if (e1 > e_cnt) e1 = e_cnt;
    if (e0 >= e_cnt) return;
    int imode = flags[1];
    for (int i = t; i < nb; i += 256) hist[i] = 0;
    __syncthreads();
    // phase 1: LDS histogram of this chunk
    for (int e = e0 + t; e < e1; e += 256) {
        int r = fetch_idx(row, e, imode);
        if ((unsigned)r < (unsigned)n) atomicAdd(&hist[r >> shift], 1);
    }
    __syncthreads();
    // phase 2: reserve one contiguous range per bucket (1 global atomic each)
    for (int i = t; i < nb; i += 256) {
        int c = hist[i];
        base[i] = c ? atomicAdd(&bcur[i], c) : 0;
        hist[i] = 0;  // reuse as within-block cursor
    }
    __syncthreads();
    // phase 3: scatter into reserved ranges (block-contiguous writes)
    for (int e = e0 + t; e < e1; e += 256) {
        int r = fetch_idx(row, e, imode);
        if ((unsigned)r >= (unsigned)n) continue;
        int c = fetch_idx(col, e, imode);
        if ((unsigned)c >= (unsigned)n) c = 0;
        int bk = r >> shift;
        int pos = base[bk] + atomicAdd(&hist[bk], 1);
        rcbin[pos] = make_int2(r, c);
        valbin[pos] = vals[e];
    }
}

// One block per bucket. rows-per-bucket <= 1024.
__global__ __launch_bounds__(256) void csr_finalize(const int* __restrict__ bptr,
                                                    const int2* __restrict__ rcbin,
                                                    const float* __restrict__ valbin, int n,
                                                    int shift, int* __restrict__ row_ptr,
                                                    int* __restrict__ col_s,
                                                    float* __restrict__ val_s) {
    __shared__ int cnt[1024];
    __shared__ int curs[1024];
    __shared__ int red[256];
    int b = blockIdx.x, t = threadIdx.x;
    int rpb = 1 << shift;
    int r0 = b << shift;
    int rows = n - r0;
    if (rows <= 0) return;
    if (rows > rpb) rows = rpb;
    int ebase = bptr[b], eend = bptr[b + 1];
    for (int i = t; i < rows; i += 256) cnt[i] = 0;
    __syncthreads();
    for (int e = ebase + t; e < eend; e += 256) atomicAdd(&cnt[rcbin[e].x - r0], 1);
    __syncthreads();
    // exclusive scan of cnt[0..rows): 4 values per thread + block scan
    int v[4], s = 0;
#pragma unroll
    for (int j = 0; j < 4; j++) {
        int idx = t * 4 + j;
        v[j] = (idx < rows) ? cnt[idx] : 0;
        s += v[j];
    }
    red[t] = s;
    __syncthreads();
    for (int off = 1; off < 256; off <<= 1) {
        int u = (t >= off) ? red[t - off] : 0;
        __syncthreads();
        red[t] += u;
        __syncthreads();
    }
    int run = ebase + red[t] - s;
#pragma unroll
    for (int j = 0; j < 4; j++) {
        int idx = t * 4 + j;
        if (idx < rows) {
            row_ptr[r0 + idx] = run;
            curs[idx] = run;
            run += v[j];
        }
    }
    __syncthreads();
    for (int e = ebase + t; e < eend; e += 256) {
        int2 rc = rcbin[e];
        float vv = valbin[e];
        int pos = atomicAdd(&curs[rc.x - r0], 1);
        col_s[pos] = rc.y;
        val_s[pos] = vv;
    }
}

// ---------------- SpMM: ax = A @ x  (CSR, one wave per row) ----------------
// Latency-bound fix (round 1 counters: HBM 10%, VALU 19%): preload up to 64
// (col,val) per row into registers (1/lane), shfl-broadcast -> no load-to-
// address chain. 4 x 16-lane groups each gather a DIFFERENT edge as float4
// (16 lanes x 16B = 256B row), 2-deep unrolled = 8 gathers in flight/wave.

__global__ __launch_bounds__(256) void spmm_dual(const float* __restrict__ X,
                                                 const int* __restrict__ row_ptr,
                                                 const int* __restrict__ col_s,
                                                 const float* __restrict__ val_s,
                                                 const unsigned char* __restrict__ mask, int n,
                                                 float* __restrict__ ax_m,
                                                 float* __restrict__ ax_f) {
    int gid = blockIdx.x * 256 + threadIdx.x;
    int r = gid >> 6;
    if (r >= n) return;
    int lane = threadIdx.x & 63;
    int g = lane >> 4, sub = lane & 15;
    int s = row_ptr[r], e = row_ptr[r + 1];
    int cnt = e - s;
    int myc = 0;
    float myvf = 0.f, myvm = 0.f;
    if (lane < cnt) {
        myc = col_s[s + lane];
        float v = val_s[s + lane];
        myvf = v;
        myvm = mask[myc] ? 0.f : v;
    }
    int cmain = cnt > 64 ? 64 : cnt;
    float4 fA = {0, 0, 0, 0}, fB = {0, 0, 0, 0}, mA = {0, 0, 0, 0}, mB = {0, 0, 0, 0};
    for (int i = 0; i < cmain; i += 8) {
        int iA = i + g, iB = i + 4 + g;
        int cA = __shfl(myc, iA), cB = __shfl(myc, iB);
        float vfA = __shfl(myvf, iA), vfB = __shfl(myvf, iB);
        float vmA = __shfl(myvm, iA), vmB = __shfl(myvm, iB);
        if (iA < cmain) {
            float4 x = *(const float4*)(X + (size_t)cA * 64 + sub * 4);
            fma4(fA, vfA, x);
            fma4(mA, vmA, x);
        }
        if (iB < cmain) {
            float4 x = *(const float4*)(X + (size_t)cB * 64 + sub * 4);
            fma4(fB, vfB, x);
            fma4(mB, vmB, x);
        }
    }
    for (int i = 64 + g; i < cnt; i += 4) {  // rare overflow rows
        int c = col_s[s + i];
        float v = val_s[s + i];
        float vm = mask[c] ? 0.f : v;
        float4 x = *(const float4*)(X + (size_t)c * 64 + sub * 4);
        fma4(fA, v, x);
        fma4(mA, vm, x);
    }
    fA.x += fB.x; fA.y += fB.y; fA.z += fB.z; fA.w += fB.w;
    mA.x += mB.x; mA.y += mB.y; mA.z += mB.z; mA.w += mB.w;
    red4(fA);
    red4(mA);
    if (g == 0) {
        *(float4*)(ax_f + (size_t)r * 64 + sub * 4) = fA;
        *(float4*)(ax_m + (size_t)r * 64 + sub * 4) = mA;
    }
}

// Single-output masked SpMM; masked edges skip the gather entirely
// (group-uniform predicate -> no memory transaction issued).
__global__ __launch_bounds__(256) void spmm_one(const float* __restrict__ X,
                                                const int* __restrict__ row_ptr,
                                                const int* __restrict__ col_s,
                                                const float* __restrict__ val_s,
                                                const unsigned char* __restrict__ mask, int n,
                                                float* __restrict__ ax) {
    int gid = blockIdx.x * 256 + threadIdx.x;
    int r = gid >> 6;
    if (r >= n) return;
    int lane = threadIdx.x & 63;
    int g = lane >> 4, sub = lane & 15;
    int s = row_ptr[r], e = row_ptr[r + 1];
    int cnt = e - s;
    int myc = 0;
    float myv = 0.f;
    if (lane < cnt) {
        myc = col_s[s + lane];
        float v = val_s[s + lane];
        myv = mask[myc] ? 0.f : v;
    }
    int cmain = cnt > 64 ? 64 : cnt;
    float4 aA = {0, 0, 0, 0}, aB = {0, 0, 0, 0};
    for (int i = 0; i < cmain; i += 8) {
        int iA = i + g, iB = i + 4 + g;
        int cA = __shfl(myc, iA), cB = __shfl(myc, iB);
        float vA = __shfl(myv, iA), vB = __shfl(myv, iB);
        if (iA < cmain && vA != 0.f) {
            float4 x = *(const float4*)(X + (size_t)cA * 64 + sub * 4);
            fma4(aA, vA, x);
        }
        if (iB < cmain && vB != 0.f) {
            float4 x = *(const float4*)(X + (size_t)cB * 64 + sub * 4);
            fma4(aB, vB, x);
        }
    }
    for (int i = 64 + g; i < cnt; i += 4) {
        int c = col_s[s + i];
        if (mask[c]) continue;
        float v = val_s[s + i];
        float4 x = *(const float4*)(X + (size_t)c * 64 + sub * 4);
        fma4(aA, v, x);
    }
    aA.x += aB.x; aA.y += aB.y; aA.z += aB.z; aA.w += aB.w;
    red4(aA);
    if (g == 0) *(float4*)(ax + (size_t)r * 64 + sub * 4) = aA;
}

// ---------------- fused kernel A: embed GEMM (bias+PReLU) -> LDS -> fc GEMM -> tanh-sum -----
// embed tile (16 rows x 64 cols, f32, stride 68 -> conflict-free b128 reads)
// lives only in LDS. s_sums[p][k] += sum_rows tanh(fc(embed)).

template <int PP>
__global__ __launch_bounds__(256) void gemm_tanh(const float* __restrict__ X,
                                                 const float* __restrict__ Wg,
                                                 const float* __restrict__ b,
                                                 const float* __restrict__ a,
                                                 const float* __restrict__ fcw,
                                                 const float* __restrict__ fcb, int n,
                                                 float* __restrict__ s_sums) {
    __shared__ __align__(16) float tile[PP][16][68];
    int t = threadIdx.x;
    int wv = t >> 6, lane = t & 63, nl = lane & 15, q = lane >> 4;
    int colg = wv * 16 + nl;
    bf16x8 whi[PP][2], wlo[PP][2];
    float bias[PP], slope[PP];
#pragma unroll
    for (int p = 0; p < PP; p++) {
#pragma unroll
        for (int kk = 0; kk < 2; kk++)
            split8(Wg + p * 4096 + colg * 64 + kk * 32 + q * 8, true, whi[p][kk], wlo[p][kk]);
        bias[p] = b[p * 64 + colg];
        slope[p] = a[p];
    }
    bf16x8 fhi[2], flo[2];
#pragma unroll
    for (int kk = 0; kk < 2; kk++)
        split8(fcw + colg * 64 + kk * 32 + q * 8, true, fhi[kk], flo[kk]);
    float fbias = fcb[colg];
    float ssum[PP];
#pragma unroll
    for (int p = 0; p < PP; p++) ssum[p] = 0.f;

    int ntiles = (n + 15) >> 4;
    for (int rt = blockIdx.x; rt < ntiles; rt += gridDim.x) {
        int rowi = rt * 16 + nl;
        bool ok = rowi < n;
        bf16x8 ah[2], al[2];
#pragma unroll
        for (int kk = 0; kk < 2; kk++)
            split8(X + (size_t)rowi * 64 + kk * 32 + q * 8, ok, ah[kk], al[kk]);
#pragma unroll
        for (int p = 0; p < PP; p++) {
            f32x4 acc = {0.f, 0.f, 0.f, 0.f};
            acc = __builtin_amdgcn_mfma_f32_16x16x32_bf16(ah[0], whi[p][0], acc, 0, 0, 0);
            acc = __builtin_amdgcn_mfma_f32_16x16x32_bf16(ah[1], whi[p][1], acc, 0, 0, 0);
            acc = __builtin_amdgcn_mfma_f32_16x16x32_bf16(al[0], whi[p][0], acc, 0, 0, 0);
            acc = __builtin_amdgcn_mfma_f32_16x16x32_bf16(al[1], whi[p][1], acc, 0, 0, 0);
            acc = __builtin_amdgcn_mfma_f32_16x16x32_bf16(ah[0], wlo[p][0], acc, 0, 0, 0);
            acc = __builtin_amdgcn_mfma_f32_16x16x32_bf16(ah[1], wlo[p][1], acc, 0, 0, 0);
            acc = __builtin_amdgcn_mfma_f32_16x16x32_bf16(al[0], wlo[p][0], acc, 0, 0, 0);
            acc = __builtin_amdgcn_mfma_f32_16x16x32_bf16(al[1], wlo[p][1], acc, 0, 0, 0);
#pragma unroll
            for (int i = 0; i < 4; i++) {
                float o = acc[i] + bias[p];
                tile[p][q * 4 + i][colg] = (o > 0.f) ? o : slope[p] * o;
            }
        }
        __syncthreads();
#pragma unroll
        for (int p = 0; p < PP; p++) {
            bf16x8 eh[2], el[2];
#pragma unroll
            for (int kk = 0; kk < 2; kk++)
                split8(&tile[p][nl][kk * 32 + q * 8], true, eh[kk], el[kk]);
            f32x4 acc = {0.f, 0.f, 0.f, 0.f};
            acc = __builtin_amdgcn_mfma_f32_16x16x32_bf16(eh[0], fhi[0], acc, 0, 0, 0);
            acc = __builtin_amdgcn_mfma_f32_16x16x32_bf16(eh[1], fhi[1], acc, 0, 0, 0);
            acc = __builtin_amdgcn_mfma_f32_16x16x32_bf16(el[0], fhi[0], acc, 0, 0, 0);
            acc = __builtin_amdgcn_mfma_f32_16x16x32_bf16(el[1], fhi[1], acc, 0, 0, 0);
            acc = __builtin_amdgcn_mfma_f32_16x16x32_bf16(eh[0], flo[0], acc, 0, 0, 0);
            acc = __builtin_amdgcn_mfma_f32_16x16x32_bf16(eh[1], flo[1], acc, 0, 0, 0);
#pragma unroll
            for (int i = 0; i < 4; i++) {
                int r = rt * 16 + q * 4 + i;
                if (r < n) ssum[p] += fast_tanh(acc[i] + fbias);
            }
        }
        __syncthreads();
    }
#pragma unroll
    for (int p = 0; p < PP; p++) {
        float s = ssum[p];
        s += __shfl_xor(s, 16);
        s += __shfl_xor(s, 32);
        if (q == 0) atomicAdd(&s_sums[p * 64 + colg], s);
    }
}

// ---------------- fused kernel B: recompute embed GEMM, mix with beta, write out -----------

template <int PP>
__global__ __launch_bounds__(256) void gemm_mix(const float* __restrict__ X,
                                                const float* __restrict__ Wg,
                                                const float* __restrict__ b,
                                                const float* __restrict__ a,
                                                const float* __restrict__ beta, int n,
                                                float* __restrict__ out, int accum) {
    int t = threadIdx.x;
    int wv = t >> 6, lane = t & 63, nl = lane & 15, q = lane >> 4;
    int colg = wv * 16 + nl;
    bf16x8 whi[PP][2], wlo[PP][2];
    float bias[PP], slope[PP], bet[PP];
#pragma unroll
    for (int p = 0; p < PP; p++) {
#pragma unroll
        for (int kk = 0; kk < 2; kk++)
            split8(Wg + p * 4096 + colg * 64 + kk * 32 + q * 8, true, whi[p][kk], wlo[p][kk]);
        bias[p] = b[p * 64 + colg];
        slope[p] = a[p];
        bet[p] = beta[p];
    }
    int ntiles = (n + 15) >> 4;
    for (int rt = blockIdx.x; rt < ntiles; rt += gridDim.x) {
        int rowi = rt * 16 + nl;
        bool ok = rowi < n;
        bf16x8 ah[2], al[2];
#pragma unroll
        for (int kk = 0; kk < 2; kk++)
            split8(X + (size_t)rowi * 64 + kk * 32 + q * 8, ok, ah[kk], al[kk]);
        float mix[4] = {0.f, 0.f, 0.f, 0.f};
#pragma unroll
        for (int p = 0; p < PP; p++) {
            f32x4 acc = {0.f, 0.f, 0.f, 0.f};
            acc = __builtin_amdgcn_mfma_f32_16x16x32_bf16(ah[0], whi[p][0], acc, 0, 0, 0);
            acc = __builtin_amdgcn_mfma_f32_16x16x32_bf16(ah[1], whi[p][1], acc, 0, 0, 0);
            acc = __builtin_amdgcn_mfma_f32_16x16x32_bf16(al[0], whi[p][0], acc, 0, 0, 0);
            acc = __builtin_amdgcn_mfma_f32_16x16x32_bf16(al[1], whi[p][1], acc, 0, 0, 0);
            acc = __builtin_amdgcn_mfma_f32_16x16x32_bf16(ah[0], wlo[p][0], acc, 0, 0, 0);
            acc = __builtin_amdgcn_mfma_f32_16x16x32_bf16(ah[1], wlo[p][1], acc, 0, 0, 0);
            acc = __builtin_amdgcn_mfma_f32_16x16x32_bf16(al[0], wlo[p][0], acc, 0, 0, 0);
            acc = __builtin_amdgcn_mfma_f32_16x16x32_bf16(al[1], wlo[p][1], acc, 0, 0, 0);
#pragma unroll
            for (int i = 0; i < 4; i++) {
                float o = acc[i] + bias[p];
                o = (o > 0.f) ? o : slope[p] * o;
                mix[i] = fmaf(bet[p], o, mix[i]);
            }
        }
#pragma unroll
        for (int i = 0; i < 4; i++) {
            int r = rt * 16 + q * 4 + i;
            if (r < n) {
                size_t idx = (size_t)r * 64 + colg;
                out[idx] = accum ? (out[idx] + mix[i]) : mix[i];
            }
        }
    }
}

__global__ __launch_bounds__(64) void compute_beta(const float* __restrict__ s_sums,
                                                   const float* __restrict__ att, int n, int P,
                                                   float* __restrict__ beta) {
    int lane = threadIdx.x;
    float av = att[lane];
    float l[8];
    for (int p = 0; p < P; p++) l[p] = s_sums[p * 64 + lane] * av;
#pragma unroll
    for (int off = 32; off > 0; off >>= 1)
        for (int p = 0; p < 8; p++)
            if (p < P) l[p] += __shfl_down(l[p], off);
    if (lane == 0) {
        const float inv = 1.0f / (float)n;
        float m = -1e30f;
        for (int p = 0; p < P; p++) {
            l[p] *= inv;
            m = fmaxf(m, l[p]);
        }
        float s = 0.f;
        for (int p = 0; p < P; p++) {
            l[p] = __expf(l[p] - m);
            s += l[p];
        }
        for (int p = 0; p < P; p++) beta[p] = l[p] / s;
    }
}

// ---------------- driver ----------------

extern "C" void kernel_launch(void* const* d_in, const int* in_sizes, int n_in,
                              void* d_out, int out_size, void* d_ws, size_t ws_size,
                              hipStream_t stream) {
    const float* h = (const float*)d_in[0];
    const float* W = (const float*)d_in[1];
    const float* b = (const float*)d_in[2];
    const float* a = (const float*)d_in[3];
    const float* fc_w = (const float*)d_in[4];
    const float* fc_b = (const float*)d_in[5];
    const float* att = (const float*)d_in[6];
    const float* adj = (const float*)d_in[7];
    const void* row = d_in[8];
    const void* col = d_in[9];
    const void* mask1 = d_in[10];
    const void* mask2 = d_in[11];
    float* out = (float*)d_out;

    int P = in_sizes[3];
    if (P < 1 || P > 8) P = 3;
    int N = in_sizes[0] / 64;
    int E = in_sizes[7];

    // bucket geometry: rows/bucket = 1<<shift, buckets <= 2048, rows/bucket <= 1024
    int shift = 8;
    while (((N >> shift) + 1) > 2048) shift++;
    int NB = (N >> shift) + 1;

    char* w = (char*)d_ws;
    auto alloc = [&](size_t bytes) {
        void* p = (void*)w;
        w += (bytes + 255) & ~(size_t)255;
        return p;
    };
    int* row_ptr = (int*)alloc((size_t)(N + 1) * 4);
    int* col_s = (int*)alloc((size_t)E * 4);
    float* val_s = (float*)alloc((size_t)E * 4);
    int* bptr = (int*)alloc((size_t)(NB + 1) * 4);
    int* bcur = (int*)alloc((size_t)NB * 4);
    int2* rcbin = (int2*)alloc((size_t)E * 8);
    float* valbin = (float*)alloc((size_t)E * 4);
    unsigned char* m1c = (unsigned char*)alloc(N);
    unsigned char* m2c = (unsigned char*)alloc(N);
    float* axm = (float*)alloc((size_t)N * 64 * 4);  // A @ (x * ~mask)
    float* axf = (float*)alloc((size_t)N * 64 * 4);  // A @ x
    float* s_sums = (float*)alloc(8 * 64 * 4);
    float* beta = (float*)alloc(8 * 4);
    int* flags = (int*)alloc(256);

    int nw_mask = N / 4 > 25000 ? 25000 : N / 4;
    int nw_idx = E / 4 > 25000 ? 25000 : E / 4;
    forensic_kernel<<<1, 256, 0, stream>>>((const unsigned int*)mask1, (const unsigned int*)row,
                                           nw_mask, nw_idx, flags);
    conv_mask_kernel<<<(N + 255) / 256, 256, 0, stream>>>(mask1, flags, N, m1c);
    conv_mask_kernel<<<(N + 255) / 256, 256, 0, stream>>>(mask2, flags, N, m2c);

    hipMemsetAsync(bptr, 0, (size_t)(NB + 1) * 4, stream);
    bucket_hist<<<1024, 256, 0, stream>>>(row, flags, E, N, shift, NB, bptr);
    bucket_scan<<<1, 1024, 0, stream>>>(bptr, NB, bcur, N, row_ptr);
    int epb = 8192;
    int bin_blocks = (E + epb - 1) / epb;
    bin_pass2<<<bin_blocks, 256, 0, stream>>>(row, col, adj, flags, E, N, shift, NB, epb, bcur,
                                              rcbin, valbin);
    csr_finalize<<<NB, 256, 0, stream>>>(bptr, rcbin, valbin, N, shift, row_ptr, col_s, val_s);

    int spmm_grid = ((size_t)N * 64 + 255) / 256;  // one wave per row
    int gemm_blocks = 1024;

    // tail: ax -> [A: embed GEMM + fc + tanh-sum] -> beta -> [B: recompute + mix]
    auto tail = [&](const float* ax, float* dst) {
        hipMemsetAsync(s_sums, 0, 8 * 64 * 4, stream);
        if (P == 3) {
            gemm_tanh<3><<<gemm_blocks, 256, 0, stream>>>(ax, W, b, a, fc_w, fc_b, N, s_sums);
        } else {
            for (int p = 0; p < P; p++)
                gemm_tanh<1><<<gemm_blocks, 256, 0, stream>>>(ax, W + p * 4096, b + p * 64, a + p,
                                                              fc_w, fc_b, N, s_sums + p * 64);
        }
        compute_beta<<<1, 64, 0, stream>>>(s_sums, att, N, P, beta);
        if (P == 3) {
            gemm_mix<3><<<gemm_blocks, 256, 0, stream>>>(ax, W, b, a, beta, N, dst, 0);
        } else {
            for (int p = 0; p < P; p++)
                gemm_mix<1><<<gemm_blocks, 256, 0, stream>>>(ax, W + p * 4096, b + p * 64, a + p,
                                                             beta + p, N, dst, p != 0);
        }
    };

    // pass 0 + 1 share one edge sweep: ax_masked and ax_full from a single gather
    spmm_dual<<<spmm_grid, 256, 0, stream>>>(h, row_ptr, col_s, val_s, m1c, N, axm, axf);
    tail(axm, out);                       // z_mp
    tail(axf, out + (size_t)N * 64);      // z_mp2
    // pass 2 decodes from z_mp (in d_out), masked by mask2 (gather skipped when masked)
    spmm_one<<<spmm_grid, 256, 0, stream>>>(out, row_ptr, col_s, val_s, m2c, N, axm);
    tail(axm, out + (size_t)2 * N * 64);  // x_recon
}

// Round 5
// 652.835 us; speedup vs baseline: 1.7391x; 1.0044x over previous
//
#include <hip/hip_runtime.h>
#include <hip/hip_bf16.h>

typedef __hip_bfloat16 bf16;
typedef __attribute__((ext_vector_type(8))) short bf16x8;  // 8 bf16 in 4 VGPRs
typedef __attribute__((ext_vector_type(4))) float f32x4;

// ---------------- bf16 split helpers (Ootomo bf16x3 scheme) ----------------

__device__ __forceinline__ short f2bf(float x) {  // RNE float->bf16 bits
    unsigned u = __float_as_uint(x);
    unsigned r = (u + 0x7FFFu + ((u >> 16) & 1u)) >> 16;
    return (short)r;
}
__device__ __forceinline__ float bf2f(short s) {
    return __uint_as_float(((unsigned)(unsigned short)s) << 16);
}

// Load 8 consecutive floats (16B-aligned), split into hi/lo bf16 fragments.
__device__ __forceinline__ void split8(const float* __restrict__ p, bool ok, bf16x8& hi,
                                       bf16x8& lo) {
    float v[8];
    if (ok) {
        float4 x0 = ((const float4*)p)[0];
        float4 x1 = ((const float4*)p)[1];
        v[0] = x0.x; v[1] = x0.y; v[2] = x0.z; v[3] = x0.w;
        v[4] = x1.x; v[5] = x1.y; v[6] = x1.z; v[7] = x1.w;
    } else {
#pragma unroll
        for (int j = 0; j < 8; j++) v[j] = 0.f;
    }
#pragma unroll
    for (int j = 0; j < 8; j++) {
        short hb = f2bf(v[j]);
        hi[j] = hb;
        lo[j] = f2bf(v[j] - bf2f(hb));
    }
}

__device__ __forceinline__ float fast_tanh(float x) {
    x = fminf(fmaxf(x, -15.f), 15.f);
    float t = __expf(2.f * x);
    return __fdividef(t - 1.f, t + 1.f);
}

__device__ __forceinline__ void fma4(float4& acc, float v, const float4& x) {
    acc.x = fmaf(v, x.x, acc.x);
    acc.y = fmaf(v, x.y, acc.y);
    acc.z = fmaf(v, x.z, acc.z);
    acc.w = fmaf(v, x.w, acc.w);
}

__device__ __forceinline__ void red4(float4& a) {
    a.x += __shfl_xor(a.x, 16); a.y += __shfl_xor(a.y, 16);
    a.z += __shfl_xor(a.z, 16); a.w += __shfl_xor(a.w, 16);
    a.x += __shfl_xor(a.x, 32); a.y += __shfl_xor(a.y, 32);
    a.z += __shfl_xor(a.z, 32); a.w += __shfl_xor(a.w, 32);
}

// ---------------- dtype forensics (masks / indices) ----------------
// modes: 0=u8/bool, 1=int32, 2=float32, 3=int64, 4=float64
__global__ __launch_bounds__(256) void forensic_kernel(const unsigned int* __restrict__ mask_w,
                                                       const unsigned int* __restrict__ idx_w,
                                                       int nw_mask, int nw_idx,
                                                       int* __restrict__ flags) {
    __shared__ int sm[6];
    int t = threadIdx.x;
    if (t < 6) sm[t] = 0;
    __syncthreads();
    int m_gt1 = 0, m_f32 = 0, m_f64 = 0, m_oddnz = 0, i_hi = 0, i_oddnz = 0;
    for (int i = t; i < nw_mask; i += 256) {
        unsigned int w = mask_w[i];
        if (w > 1u && w != 0x3F800000u && w != 0x3FF00000u) m_gt1++;
        if (w == 0x3F800000u) m_f32++;
        if ((i & 1) && w == 0x3FF00000u) m_f64++;
        if ((i & 1) && w != 0u) m_oddnz++;
    }
    for (int i = t; i < nw_idx; i += 256) {
        unsigned int v = idx_w[i];
        if (v >= 0x20000000u) i_hi++;
        if ((i & 1) && v != 0u) i_oddnz++;
    }
    atomicAdd(&sm[0], m_gt1);
    atomicAdd(&sm[1], m_f32);
    atomicAdd(&sm[2], m_f64);
    atomicAdd(&sm[3], m_oddnz);
    atomicAdd(&sm[4], i_hi);
    atomicAdd(&sm[5], i_oddnz);
    __syncthreads();
    if (t == 0) {
        int mmode;
        if (sm[1] > 50) mmode = 2;
        else if (sm[2] > 50) mmode = 4;
        else if (sm[0] > 50) mmode = 0;
        else if (sm[3] > 50) mmode = 1;
        else mmode = 3;
        int imode;
        if (sm[4] > (nw_idx * 3) / 4) imode = 2;
        else if (sm[4] > nw_idx / 4) imode = 4;
        else if (sm[5] > 50) imode = 1;
        else imode = 3;
        flags[0] = mmode;
        flags[1] = imode;
    }
}

__device__ __forceinline__ int fetch_idx(const void* p, int e, int mode) {
    switch (mode) {
        case 1: return ((const int*)p)[e];
        case 3: return (int)(((const long long*)p)[e]);
        case 2: return (int)(((const float*)p)[e]);
        default: return (int)(((const double*)p)[e]);
    }
}

__device__ __forceinline__ bool conv_one(const void* m, int mode, int i) {
    switch (mode) {
        case 0: return ((const unsigned char*)m)[i] != 0;
        case 1: return ((const int*)m)[i] != 0;
        case 2: return ((const float*)m)[i] != 0.f;
        case 3: return ((const long long*)m)[i] != 0;
        default: return ((const double*)m)[i] != 0.0;
    }
}

// Both masks in one launch.
__global__ __launch_bounds__(256) void conv_masks(const void* __restrict__ m1,
                                                  const void* __restrict__ m2,
                                                  const int* __restrict__ flags, int n,
                                                  unsigned char* __restrict__ o1,
                                                  unsigned char* __restrict__ o2) {
    int mode = flags[0];
    int i = blockIdx.x * 256 + threadIdx.x;
    if (i >= n) return;
    o1[i] = conv_one(m1, mode, i) ? 1 : 0;
    o2[i] = conv_one(m2, mode, i) ? 1 : 0;
}

// ---------------- CSR build: two-level bucket sort, block-aggregated binning --------
// Round-4 post-mortem: bin_pass2 at 5% occupancy (196 blocks) was pure grid
// starvation. Fix: 2048 edges/block (784 blocks ~3/CU) + per-thread register
// cache of the 8 edges (no phase-3 global re-read). csr_finalize: 512 threads.

__global__ __launch_bounds__(256) void bucket_hist(const void* __restrict__ row,
                                                   const int* __restrict__ flags, int e_cnt,
                                                   int n, int shift, int nb,
                                                   int* __restrict__ bcnt) {
    __shared__ int hist[2048];
    int t = threadIdx.x;
    for (int i = t; i < nb; i += 256) hist[i] = 0;
    __syncthreads();
    int imode = flags[1];
    for (int e = blockIdx.x * 256 + t; e < e_cnt; e += gridDim.x * 256) {
        int r = fetch_idx(row, e, imode);
        if ((unsigned)r < (unsigned)n) atomicAdd(&hist[r >> shift], 1);
    }
    __syncthreads();
    for (int i = t; i < nb; i += 256)
        if (hist[i]) atomicAdd(&bcnt[i], hist[i]);
}

// bptr: in = counts, out = exclusive offsets; also fills bcur and row_ptr[n].
__global__ __launch_bounds__(1024) void bucket_scan(int* __restrict__ bptr, int nb,
                                                    int* __restrict__ bcur, int n,
                                                    int* __restrict__ row_ptr) {
    __shared__ int sh[1024];
    int t = threadIdx.x;
    int i0 = t * 2, i1 = t * 2 + 1;
    int a = (i0 < nb) ? bptr[i0] : 0;
    int b = (i1 < nb) ? bptr[i1] : 0;
    int s = a + b;
    sh[t] = s;
    __syncthreads();
    for (int off = 1; off < 1024; off <<= 1) {
        int u = (t >= off) ? sh[t - off] : 0;
        __syncthreads();
        sh[t] += u;
        __syncthreads();
    }
    int base = sh[t] - s;  // exclusive prefix
    if (i0 < nb) { bptr[i0] = base; bcur[i0] = base; }
    if (i1 < nb) { bptr[i1] = base + a; bcur[i1] = base + a; }
    if (t == 1023) {
        bptr[nb] = sh[1023];
        row_ptr[n] = sh[1023];
    }
}

// Block-aggregated binning; 2048 edges/block, register-cached.
__global__ __launch_bounds__(256) void bin_pass2(const void* __restrict__ row,
                                                 const void* __restrict__ col,
                                                 const float* __restrict__ vals,
                                                 const int* __restrict__ flags, int e_cnt, int n,
                                                 int shift, int nb, int* __restrict__ bcur,
                                                 int2* __restrict__ rcbin,
                                                 float* __restrict__ valbin) {
    __shared__ int hist[2048];
    __shared__ int base[2048];
    int t = threadIdx.x;
    int e0 = blockIdx.x * 2048;
    if (e0 >= e_cnt) return;
    int imode = flags[1];
    for (int i = t; i < nb; i += 256) hist[i] = 0;
    __syncthreads();
    // phase 1: load this thread's 8 edges into registers + LDS histogram
    int rr[8], cc[8];
    float vv[8];
    bool ok[8];
#pragma unroll
    for (int j = 0; j < 8; j++) {
        int e = e0 + j * 256 + t;
        ok[j] = false;
        if (e < e_cnt) {
            int r = fetch_idx(row, e, imode);
            if ((unsigned)r < (unsigned)n) {
                ok[j] = true;
                rr[j] = r;
                int c = fetch_idx(col, e, imode);
                cc[j] = ((unsigned)c < (unsigned)n) ? c : 0;
                vv[j] = vals[e];
                atomicAdd(&hist[r >> shift], 1);
            }
        }
    }
    __syncthreads();
    // phase 2: reserve one contiguous range per bucket (1 global atomic each)
    for (int i = t; i < nb; i += 256) {
        int c = hist[i];
        base[i] = c ? atomicAdd(&bcur[i], c) : 0;
        hist[i] = 0;  // reuse as within-block cursor
    }
    __syncthreads();
    // phase 3: scatter from registers into reserved ranges
#pragma unroll
    for (int j = 0; j < 8; j++) {
        if (ok[j]) {
            int bk = rr[j] >> shift;
            int pos = base[bk] + atomicAdd(&hist[bk], 1);
            rcbin[pos] = make_int2(rr[j], cc[j]);
            valbin[pos] = vv[j];
        }
    }
}

// One block per bucket, 512 threads. rows-per-bucket <= 1024.
__global__ __launch_bounds__(512) void csr_finalize(const int* __restrict__ bptr,
                                                    const int2* __restrict__ rcbin,
                                                    const float* __restrict__ valbin, int n,
                                                    int shift, int* __restrict__ row_ptr,
                                                    int* __restrict__ col_s,
                                                    float* __restrict__ val_s) {
    __shared__ int cnt[1024];
    __shared__ int curs[1024];
    __shared__ int red[512];
    int b = blockIdx.x, t = threadIdx.x;
    int rpb = 1 << shift;
    int r0 = b << shift;
    int rows = n - r0;
    if (rows <= 0) return;
    if (rows > rpb) rows = rpb;
    int ebase = bptr[b], eend = bptr[b + 1];
    for (int i = t; i < rows; i += 512) cnt[i] = 0;
    __syncthreads();
    for (int e = ebase + t; e < eend; e += 512) atomicAdd(&cnt[rcbin[e].x - r0], 1);
    __syncthreads();
    // exclusive scan of cnt[0..rows): 2 values per thread + block scan
    int v[2], s = 0;
#pragma unroll
    for (int j = 0; j < 2; j++) {
        int idx = t * 2 + j;
        v[j] = (idx < rows) ? cnt[idx] : 0;
        s += v[j];
    }
    red[t] = s;
    __syncthreads();
    for (int off = 1; off < 512; off <<= 1) {
        int u = (t >= off) ? red[t - off] : 0;
        __syncthreads();
        red[t] += u;
        __syncthreads();
    }
    int run = ebase + red[t] - s;
#pragma unroll
    for (int j = 0; j < 2; j++) {
        int idx = t * 2 + j;
        if (idx < rows) {
            row_ptr[r0 + idx] = run;
            curs[idx] = run;
            run += v[j];
        }
    }
    __syncthreads();
    for (int e = ebase + t; e < eend; e += 512) {
        int2 rc = rcbin[e];
        float vv = valbin[e];
        int pos = atomicAdd(&curs[rc.x - r0], 1);
        col_s[pos] = rc.y;
        val_s[pos] = vv;
    }
}

// ---------------- SpMM: ax = A @ x  (CSR, one wave per row) ----------------
// Register-broadcast edges; 4 x 16-lane groups each gather a different edge
// as float4; 4-deep unroll = 16 gathers in flight per wave (avg row = 16).

__global__ __launch_bounds__(256) void spmm_dual(const float* __restrict__ X,
                                                 const int* __restrict__ row_ptr,
                                                 const int* __restrict__ col_s,
                                                 const float* __restrict__ val_s,
                                                 const unsigned char* __restrict__ mask, int n,
                                                 float* __restrict__ ax_m,
                                                 float* __restrict__ ax_f) {
    int gid = blockIdx.x * 256 + threadIdx.x;
    int r = gid >> 6;
    if (r >= n) return;
    int lane = threadIdx.x & 63;
    int g = lane >> 4, sub = lane & 15;
    int s = row_ptr[r], e = row_ptr[r + 1];
    int cnt = e - s;
    int myc = 0;
    float myvf = 0.f, myvm = 0.f;
    if (lane < cnt) {
        myc = col_s[s + lane];
        float v = val_s[s + lane];
        myvf = v;
        myvm = mask[myc] ? 0.f : v;
    }
    int cmain = cnt > 64 ? 64 : cnt;
    float4 fA = {0, 0, 0, 0}, fB = {0, 0, 0, 0}, mA = {0, 0, 0, 0}, mB = {0, 0, 0, 0};
    for (int i = 0; i < cmain; i += 16) {
        int i0 = i + g, i1 = i + 4 + g, i2 = i + 8 + g, i3 = i + 12 + g;
        int c0 = __shfl(myc, i0), c1 = __shfl(myc, i1);
        int c2 = __shfl(myc, i2), c3 = __shfl(myc, i3);
        float vf0 = __shfl(myvf, i0), vf1 = __shfl(myvf, i1);
        float vf2 = __shfl(myvf, i2), vf3 = __shfl(myvf, i3);
        float vm0 = __shfl(myvm, i0), vm1 = __shfl(myvm, i1);
        float vm2 = __shfl(myvm, i2), vm3 = __shfl(myvm, i3);
        if (i0 < cmain) {
            float4 x = *(const float4*)(X + (size_t)c0 * 64 + sub * 4);
            fma4(fA, vf0, x);
            fma4(mA, vm0, x);
        }
        if (i1 < cmain) {
            float4 x = *(const float4*)(X + (size_t)c1 * 64 + sub * 4);
            fma4(fB, vf1, x);
            fma4(mB, vm1, x);
        }
        if (i2 < cmain) {
            float4 x = *(const float4*)(X + (size_t)c2 * 64 + sub * 4);
            fma4(fA, vf2, x);
            fma4(mA, vm2, x);
        }
        if (i3 < cmain) {
            float4 x = *(const float4*)(X + (size_t)c3 * 64 + sub * 4);
            fma4(fB, vf3, x);
            fma4(mB, vm3, x);
        }
    }
    for (int i = 64 + g; i < cnt; i += 4) {  // rare overflow rows
        int c = col_s[s + i];
        float v = val_s[s + i];
        float vm = mask[c] ? 0.f : v;
        float4 x = *(const float4*)(X + (size_t)c * 64 + sub * 4);
        fma4(fA, v, x);
        fma4(mA, vm, x);
    }
    fA.x += fB.x; fA.y += fB.y; fA.z += fB.z; fA.w += fB.w;
    mA.x += mB.x; mA.y += mB.y; mA.z += mB.z; mA.w += mB.w;
    red4(fA);
    red4(mA);
    if (g == 0) {
        *(float4*)(ax_f + (size_t)r * 64 + sub * 4) = fA;
        *(float4*)(ax_m + (size_t)r * 64 + sub * 4) = mA;
    }
}

// Single-output masked SpMM; masked edges skip the gather entirely.
__global__ __launch_bounds__(256) void spmm_one(const float* __restrict__ X,
                                                const int* __restrict__ row_ptr,
                                                const int* __restrict__ col_s,
                                                const float* __restrict__ val_s,
                                                const unsigned char* __restrict__ mask, int n,
                                                float* __restrict__ ax) {
    int gid = blockIdx.x * 256 + threadIdx.x;
    int r = gid >> 6;
    if (r >= n) return;
    int lane = threadIdx.x & 63;
    int g = lane >> 4, sub = lane & 15;
    int s = row_ptr[r], e = row_ptr[r + 1];
    int cnt = e - s;
    int myc = 0;
    float myv = 0.f;
    if (lane < cnt) {
        myc = col_s[s + lane];
        float v = val_s[s + lane];
        myv = mask[myc] ? 0.f : v;
    }
    int cmain = cnt > 64 ? 64 : cnt;
    float4 aA = {0, 0, 0, 0}, aB = {0, 0, 0, 0};
    for (int i = 0; i < cmain; i += 16) {
        int i0 = i + g, i1 = i + 4 + g, i2 = i + 8 + g, i3 = i + 12 + g;
        int c0 = __shfl(myc, i0), c1 = __shfl(myc, i1);
        int c2 = __shfl(myc, i2), c3 = __shfl(myc, i3);
        float v0 = __shfl(myv, i0), v1 = __shfl(myv, i1);
        float v2 = __shfl(myv, i2), v3 = __shfl(myv, i3);
        if (i0 < cmain && v0 != 0.f) {
            float4 x = *(const float4*)(X + (size_t)c0 * 64 + sub * 4);
            fma4(aA, v0, x);
        }
        if (i1 < cmain && v1 != 0.f) {
            float4 x = *(const float4*)(X + (size_t)c1 * 64 + sub * 4);
            fma4(aB, v1, x);
        }
        if (i2 < cmain && v2 != 0.f) {
            float4 x = *(const float4*)(X + (size_t)c2 * 64 + sub * 4);
            fma4(aA, v2, x);
        }
        if (i3 < cmain && v3 != 0.f) {
            float4 x = *(const float4*)(X + (size_t)c3 * 64 + sub * 4);
            fma4(aB, v3, x);
        }
    }
    for (int i = 64 + g; i < cnt; i += 4) {
        int c = col_s[s + i];
        if (mask[c]) continue;
        float v = val_s[s + i];
        float4 x = *(const float4*)(X + (size_t)c * 64 + sub * 4);
        fma4(aA, v, x);
    }
    aA.x += aB.x; aA.y += aB.y; aA.z += aB.z; aA.w += aB.w;
    red4(aA);
    if (g == 0) *(float4*)(ax + (size_t)r * 64 + sub * 4) = aA;
}

// ---------------- fused kernel A: embed GEMM (bias+PReLU) -> LDS -> fc GEMM -> tanh-sum -----

template <int PP>
__global__ __launch_bounds__(256) void gemm_tanh(const float* __restrict__ X,
                                                 const float* __restrict__ Wg,
                                                 const float* __restrict__ b,
                                                 const float* __restrict__ a,
                                                 const float* __restrict__ fcw,
                                                 const float* __restrict__ fcb, int n,
                                                 float* __restrict__ s_sums) {
    __shared__ __align__(16) float tile[PP][16][68];
    int t = threadIdx.x;
    int wv = t >> 6, lane = t & 63, nl = lane & 15, q = lane >> 4;
    int colg = wv * 16 + nl;
    bf16x8 whi[PP][2], wlo[PP][2];
    float bias[PP], slope[PP];
#pragma unroll
    for (int p = 0; p < PP; p++) {
#pragma unroll
        for (int kk = 0; kk < 2; kk++)
            split8(Wg + p * 4096 + colg * 64 + kk * 32 + q * 8, true, whi[p][kk], wlo[p][kk]);
        bias[p] = b[p * 64 + colg];
        slope[p] = a[p];
    }
    bf16x8 fhi[2], flo[2];
#pragma unroll
    for (int kk = 0; kk < 2; kk++)
        split8(fcw + colg * 64 + kk * 32 + q * 8, true, fhi[kk], flo[kk]);
    float fbias = fcb[colg];
    float ssum[PP];
#pragma unroll
    for (int p = 0; p < PP; p++) ssum[p] = 0.f;

    int ntiles = (n + 15) >> 4;
    for (int rt = blockIdx.x; rt < ntiles; rt += gridDim.x) {
        int rowi = rt * 16 + nl;
        bool ok = rowi < n;
        bf16x8 ah[2], al[2];
#pragma unroll
        for (int kk = 0; kk < 2; kk++)
            split8(X + (size_t)rowi * 64 + kk * 32 + q * 8, ok, ah[kk], al[kk]);
#pragma unroll
        for (int p = 0; p < PP; p++) {
            f32x4 acc = {0.f, 0.f, 0.f, 0.f};
            acc = __builtin_amdgcn_mfma_f32_16x16x32_bf16(ah[0], whi[p][0], acc, 0, 0, 0);
            acc = __builtin_amdgcn_mfma_f32_16x16x32_bf16(ah[1], whi[p][1], acc, 0, 0, 0);
            acc = __builtin_amdgcn_mfma_f32_16x16x32_bf16(al[0], whi[p][0], acc, 0, 0, 0);
            acc = __builtin_amdgcn_mfma_f32_16x16x32_bf16(al[1], whi[p][1], acc, 0, 0, 0);
            acc = __builtin_amdgcn_mfma_f32_16x16x32_bf16(ah[0], wlo[p][0], acc, 0, 0, 0);
            acc = __builtin_amdgcn_mfma_f32_16x16x32_bf16(ah[1], wlo[p][1], acc, 0, 0, 0);
            acc = __builtin_amdgcn_mfma_f32_16x16x32_bf16(al[0], wlo[p][0], acc, 0, 0, 0);
            acc = __builtin_amdgcn_mfma_f32_16x16x32_bf16(al[1], wlo[p][1], acc, 0, 0, 0);
#pragma unroll
            for (int i = 0; i < 4; i++) {
                float o = acc[i] + bias[p];
                tile[p][q * 4 + i][colg] = (o > 0.f) ? o : slope[p] * o;
            }
        }
        __syncthreads();
#pragma unroll
        for (int p = 0; p < PP; p++) {
            bf16x8 eh[2], el[2];
#pragma unroll
            for (int kk = 0; kk < 2; kk++)
                split8(&tile[p][nl][kk * 32 + q * 8], true, eh[kk], el[kk]);
            f32x4 acc = {0.f, 0.f, 0.f, 0.f};
            acc = __builtin_amdgcn_mfma_f32_16x16x32_bf16(eh[0], fhi[0], acc, 0, 0, 0);
            acc = __builtin_amdgcn_mfma_f32_16x16x32_bf16(eh[1], fhi[1], acc, 0, 0, 0);
            acc = __builtin_amdgcn_mfma_f32_16x16x32_bf16(el[0], fhi[0], acc, 0, 0, 0);
            acc = __builtin_amdgcn_mfma_f32_16x16x32_bf16(el[1], fhi[1], acc, 0, 0, 0);
            acc = __builtin_amdgcn_mfma_f32_16x16x32_bf16(eh[0], flo[0], acc, 0, 0, 0);
            acc = __builtin_amdgcn_mfma_f32_16x16x32_bf16(eh[1], flo[1], acc, 0, 0, 0);
#pragma unroll
            for (int i = 0; i < 4; i++) {
                int r = rt * 16 + q * 4 + i;
                if (r < n) ssum[p] += fast_tanh(acc[i] + fbias);
            }
        }
        __syncthreads();
    }
#pragma unroll
    for (int p = 0; p < PP; p++) {
        float s = ssum[p];
        s += __shfl_xor(s, 16);
        s += __shfl_xor(s, 32);
        if (q == 0) atomicAdd(&s_sums[p * 64 + colg], s);
    }
}

// ---------------- fused kernel B: recompute embed GEMM, mix with beta, write out -----------

template <int PP>
__global__ __launch_bounds__(256) void gemm_mix(const float* __restrict__ X,
                                                const float* __restrict__ Wg,
                                                const float* __restrict__ b,
                                                const float* __restrict__ a,
                                                const float* __restrict__ beta, int n,
                                                float* __restrict__ out, int accum) {
    int t = threadIdx.x;
    int wv = t >> 6, lane = t & 63, nl = lane & 15, q = lane >> 4;
    int colg = wv * 16 + nl;
    bf16x8 whi[PP][2], wlo[PP][2];
    float bias[PP], slope[PP], bet[PP];
#pragma unroll
    for (int p = 0; p < PP; p++) {
#pragma unroll
        for (int kk = 0; kk < 2; kk++)
            split8(Wg + p * 4096 + colg * 64 + kk * 32 + q * 8, true, whi[p][kk], wlo[p][kk]);
        bias[p] = b[p * 64 + colg];
        slope[p] = a[p];
        bet[p] = beta[p];
    }
    int ntiles = (n + 15) >> 4;
    for (int rt = blockIdx.x; rt < ntiles; rt += gridDim.x) {
        int rowi = rt * 16 + nl;
        bool ok = rowi < n;
        bf16x8 ah[2], al[2];
#pragma unroll
        for (int kk = 0; kk < 2; kk++)
            split8(X + (size_t)rowi * 64 + kk * 32 + q * 8, ok, ah[kk], al[kk]);
        float mix[4] = {0.f, 0.f, 0.f, 0.f};
#pragma unroll
        for (int p = 0; p < PP; p++) {
            f32x4 acc = {0.f, 0.f, 0.f, 0.f};
            acc = __builtin_amdgcn_mfma_f32_16x16x32_bf16(ah[0], whi[p][0], acc, 0, 0, 0);
            acc = __builtin_amdgcn_mfma_f32_16x16x32_bf16(ah[1], whi[p][1], acc, 0, 0, 0);
            acc = __builtin_amdgcn_mfma_f32_16x16x32_bf16(al[0], whi[p][0], acc, 0, 0, 0);
            acc = __builtin_amdgcn_mfma_f32_16x16x32_bf16(al[1], whi[p][1], acc, 0, 0, 0);
            acc = __builtin_amdgcn_mfma_f32_16x16x32_bf16(ah[0], wlo[p][0], acc, 0, 0, 0);
            acc = __builtin_amdgcn_mfma_f32_16x16x32_bf16(ah[1], wlo[p][1], acc, 0, 0, 0);
            acc = __builtin_amdgcn_mfma_f32_16x16x32_bf16(al[0], wlo[p][0], acc, 0, 0, 0);
            acc = __builtin_amdgcn_mfma_f32_16x16x32_bf16(al[1], wlo[p][1], acc, 0, 0, 0);
#pragma unroll
            for (int i = 0; i < 4; i++) {
                float o = acc[i] + bias[p];
                o = (o > 0.f) ? o : slope[p] * o;
                mix[i] = fmaf(bet[p], o, mix[i]);
            }
        }
#pragma unroll
        for (int i = 0; i < 4; i++) {
            int r = rt * 16 + q * 4 + i;
            if (r < n) {
                size_t idx = (size_t)r * 64 + colg;
                out[idx] = accum ? (out[idx] + mix[i]) : mix[i];
            }
        }
    }
}

__global__ __launch_bounds__(64) void compute_beta(const float* __restrict__ s_sums,
                                                   const float* __restrict__ att, int n, int P,
                                                   float* __restrict__ beta) {
    int lane = threadIdx.x;
    float av = att[lane];
    float l[8];
    for (int p = 0; p < P; p++) l[p] = s_sums[p * 64 + lane] * av;
#pragma unroll
    for (int off = 32; off > 0; off >>= 1)
        for (int p = 0; p < 8; p++)
            if (p < P) l[p] += __shfl_down(l[p], off);
    if (lane == 0) {
        const float inv = 1.0f / (float)n;
        float m = -1e30f;
        for (int p = 0; p < P; p++) {
            l[p] *= inv;
            m = fmaxf(m, l[p]);
        }
        float s = 0.f;
        for (int p = 0; p < P; p++) {
            l[p] = __expf(l[p] - m);
            s += l[p];
        }
        for (int p = 0; p < P; p++) beta[p] = l[p] / s;
    }
}

// ---------------- driver ----------------

extern "C" void kernel_launch(void* const* d_in, const int* in_sizes, int n_in,
                              void* d_out, int out_size, void* d_ws, size_t ws_size,
                              hipStream_t stream) {
    const float* h = (const float*)d_in[0];
    const float* W = (const float*)d_in[1];
    const float* b = (const float*)d_in[2];
    const float* a = (const float*)d_in[3];
    const float* fc_w = (const float*)d_in[4];
    const float* fc_b = (const float*)d_in[5];
    const float* att = (const float*)d_in[6];
    const float* adj = (const float*)d_in[7];
    const void* row = d_in[8];
    const void* col = d_in[9];
    const void* mask1 = d_in[10];
    const void* mask2 = d_in[11];
    float* out = (float*)d_out;

    int P = in_sizes[3];
    if (P < 1 || P > 8) P = 3;
    int N = in_sizes[0] / 64;
    int E = in_sizes[7];

    // bucket geometry: rows/bucket = 1<<shift, buckets <= 2048
    int shift = 8;
    while (((N >> shift) + 1) > 2048) shift++;
    int NB = (N >> shift) + 1;

    char* w = (char*)d_ws;
    auto alloc = [&](size_t bytes) {
        void* p = (void*)w;
        w += (bytes + 255) & ~(size_t)255;
        return p;
    };
    int* row_ptr = (int*)alloc((size_t)(N + 1) * 4);
    int* col_s = (int*)alloc((size_t)E * 4);
    float* val_s = (float*)alloc((size_t)E * 4);
    int* bptr = (int*)alloc((size_t)(NB + 1) * 4);
    int* bcur = (int*)alloc((size_t)NB * 4);
    int2* rcbin = (int2*)alloc((size_t)E * 8);
    float* valbin = (float*)alloc((size_t)E * 4);
    unsigned char* m1c = (unsigned char*)alloc(N);
    unsigned char* m2c = (unsigned char*)alloc(N);
    float* axm = (float*)alloc((size_t)N * 64 * 4);  // A @ (x * ~mask)
    float* axf = (float*)alloc((size_t)N * 64 * 4);  // A @ x
    float* s_sums = (float*)alloc(8 * 64 * 4);
    float* beta = (float*)alloc(8 * 4);
    int* flags = (int*)alloc(256);

    int nw_mask = N / 4 > 25000 ? 25000 : N / 4;
    int nw_idx = E / 4 > 25000 ? 25000 : E / 4;
    forensic_kernel<<<1, 256, 0, stream>>>((const unsigned int*)mask1, (const unsigned int*)row,
                                           nw_mask, nw_idx, flags);
    conv_masks<<<(N + 255) / 256, 256, 0, stream>>>(mask1, mask2, flags, N, m1c, m2c);

    hipMemsetAsync(bptr, 0, (size_t)(NB + 1) * 4, stream);
    bucket_hist<<<1024, 256, 0, stream>>>(row, flags, E, N, shift, NB, bptr);
    bucket_scan<<<1, 1024, 0, stream>>>(bptr, NB, bcur, N, row_ptr);
    int bin_blocks = (E + 2047) / 2048;
    bin_pass2<<<bin_blocks, 256, 0, stream>>>(row, col, adj, flags, E, N, shift, NB, bcur, rcbin,
                                              valbin);
    csr_finalize<<<NB, 512, 0, stream>>>(bptr, rcbin, valbin, N, shift, row_ptr, col_s, val_s);

    int spmm_grid = ((size_t)N * 64 + 255) / 256;  // one wave per row
    int gemm_blocks = 1536;

    // tail: ax -> [A: embed GEMM + fc + tanh-sum] -> beta -> [B: recompute + mix]
    auto tail = [&](const float* ax, float* dst) {
        hipMemsetAsync(s_sums, 0, 8 * 64 * 4, stream);
        if (P == 3) {
            gemm_tanh<3><<<gemm_blocks, 256, 0, stream>>>(ax, W, b, a, fc_w, fc_b, N, s_sums);
        } else {
            for (int p = 0; p < P; p++)
                gemm_tanh<1><<<gemm_blocks, 256, 0, stream>>>(ax, W + p * 4096, b + p * 64, a + p,
                                                              fc_w, fc_b, N, s_sums + p * 64);
        }
        compute_beta<<<1, 64, 0, stream>>>(s_sums, att, N, P, beta);
        if (P == 3) {
            gemm_mix<3><<<gemm_blocks, 256, 0, stream>>>(ax, W, b, a, beta, N, dst, 0);
        } else {
            for (int p = 0; p < P; p++)
                gemm_mix<1><<<gemm_blocks, 256, 0, stream>>>(ax, W + p * 4096, b + p * 64, a + p,
                                                             beta + p, N, dst, p != 0);
        }
    };

    // pass 0 + 1 share one edge sweep: ax_masked and ax_full from a single gather
    spmm_dual<<<spmm_grid, 256, 0, stream>>>(h, row_ptr, col_s, val_s, m1c, N, axm, axf);
    tail(axm, out);                       // z_mp
    tail(axf, out + (size_t)N * 64);      // z_mp2
    // pass 2 decodes from z_mp (in d_out), masked by mask2 (gather skipped when masked)
    spmm_one<<<spmm_grid, 256, 0, stream>>>(out, row_ptr, col_s, val_s, m2c, N, axm);
    tail(axm, out + (size_t)2 * N * 64);  // x_recon
}